// Round 14
// baseline (365.252 us; speedup 1.0000x reference)
//
#include <hip/hip_runtime.h>

#define HOUT 15
#define WOUT 15
// input  (32, 32, 32, 32, 16)  fp32
// ncv    (32, 32, 15, 15, 16)  fp32
// w      (3, 3, 32, 4, 4, 32)  fp32
// out    (32, 32, 15, 15, 16)  fp32

typedef float v2 __attribute__((ext_vector_type(2)));

// DPP butterfly add step (ctrl must be a literal). Verified rounds 1-4, 8-11.
// (All permlane-swap variants failed 3 distinct ways in rounds 5-7, 12 —
//  permanently benched. Cross-lane = shfl_xor / DPP / ds_swizzle only.)
#define DPP_ADDF(x, ctrl) \
    ((x) + __builtin_bit_cast(float, __builtin_amdgcn_update_dpp( \
        0, __builtin_bit_cast(int, (x)), (ctrl), 0xF, 0xF, true)))

// ---- explicit VOP3P packed fp32 ops (verified round 11) -------------------
__device__ __forceinline__ v2 pk_mul(v2 a, v2 b) {
    v2 d;
    asm("v_pk_mul_f32 %0, %1, %2" : "=v"(d) : "v"(a), "v"(b));
    return d;
}
__device__ __forceinline__ v2 pk_fma(v2 a, v2 b, v2 c) {
    v2 d;
    asm("v_pk_fma_f32 %0, %1, %2, %3" : "=v"(d) : "v"(a), "v"(b), "v"(c));
    return d;
}
// Broadcast forms: src0 is an SGPR pair (s_load result used directly);
// op_sel picks which element feeds lo/hi of the result.
__device__ __forceinline__ v2 pk_mul_s_lo(v2 s, v2 w) {
    v2 d;
    asm("v_pk_mul_f32 %0, %1, %2 op_sel:[0,0] op_sel_hi:[0,1]"
        : "=v"(d) : "s"(s), "v"(w));
    return d;
}
__device__ __forceinline__ v2 pk_fma_s_lo(v2 s, v2 w, v2 c) {
    v2 d;
    asm("v_pk_fma_f32 %0, %1, %2, %3 op_sel:[0,0,0] op_sel_hi:[0,1,1]"
        : "=v"(d) : "s"(s), "v"(w), "v"(c));
    return d;
}
__device__ __forceinline__ v2 pk_fma_s_hi(v2 s, v2 w, v2 c) {
    v2 d;
    asm("v_pk_fma_f32 %0, %1, %2, %3 op_sel:[1,0,0] op_sel_hi:[1,1,1]"
        : "=v"(d) : "s"(s), "v"(w), "v"(c));
    return d;
}

// ---------------- pass 0: repack w for the (m, d-half) lane mapping --------
// w[kl][n][x][d][m] -> w3[n][kl][xq][l64][e]  (147456 floats = 576 KB)
// lane l64 = m + 32*half owns d in {2*half, 2*half+1}. Element e of quad xq:
//   x = 2*xq + (e>>1), d = 2*half + (e&1)
__global__ __launch_bounds__(256) void prep_w(const float* __restrict__ wt,
                                              float* __restrict__ w3)
{
    const int t   = blockIdx.x * 256 + threadIdx.x;   // 0..147455
    const int e   = t & 3;
    const int l64 = (t >> 2) & 63;
    const int xq  = (t >> 8) & 1;
    const int r   = t >> 9;          // n*9 + kl
    const int kl  = r % 9;
    const int n   = r / 9;
    const int mm  = l64 & 31;
    const int hf  = l64 >> 5;
    const int x   = 2 * xq + (e >> 1);
    const int d   = 2 * hf + (e & 1);
    w3[t] = wt[((kl * 32 + n) * 16 + x * 4 + d) * 32 + mm];
}

// ---------------- fused kernel: one wave per output position ---------------
// Structure = round 11 (dual n-streams, SMEM av, pk-asm MACs, verified
// cross-lane set, fused LN) with TWO changes:
//  1. FOUR sites per wait-cluster (2 kl x 2 streams): the 4 ds_bpermute /
//     4 ds_swizzle are issued back-to-back so the lgkmcnt drains (which
//     also retire all in-flight s_loads — the R11 convoy) are paid ~2x
//     per 4 sites instead of 8x.
//  2. __expf (v_mul+v_exp native) instead of __builtin_exp2f's guarded
//     expansion; cv pre-scaled by 0.25 only (the verified R0-R3 form).
// NOTE: no min-waves clause (round 2: forced cap -> spill -> 3.4x regression).
__global__ __launch_bounds__(256) void caps_all(
    const float* __restrict__ input,
    const float* __restrict__ ncv,
    const float* __restrict__ w3,
    const float* __restrict__ gamma,
    const float* __restrict__ beta,
    float* __restrict__ out)
{
    const int tid  = threadIdx.x;
    const int l64  = tid & 63;
    const int m    = l64 & 31;
    const int half = l64 >> 5;

    // wave-uniform position -> SGPRs, so av loads are s_load
    const int posu = __builtin_amdgcn_readfirstlane(blockIdx.x * 4 + (tid >> 6));
    const int b  = posu / (HOUT * WOUT);
    const int hw = posu % (HOUT * WOUT);
    const int h  = hw / WOUT;
    const int wo = hw % WOUT;

    // input[b][n][h][w][16]: strides 524288 / 16384 / 512 / 16
    const float* ipb = input + (size_t)b * 524288 + (h * 2) * 512 + (wo * 2) * 16;

    // cv = ncv[b][m][h][wo][a*4 + 2*half + {0,1}], pre-scaled by 0.25
    const float* cvp = ncv + (((size_t)b * 32 + m) * (HOUT * WOUT) + hw) * 16 + 2 * half;
    v2 sc2 = {0.25f, 0.25f};
    v2 cv0 = *(const v2*)(cvp +  0) * sc2;
    v2 cv1 = *(const v2*)(cvp +  4) * sc2;
    v2 cv2 = *(const v2*)(cvp +  8) * sc2;
    v2 cv3 = *(const v2*)(cvp + 12) * sc2;

    v2 acA0 = {0.f,0.f}, acA1 = {0.f,0.f}, acA2 = {0.f,0.f}, acA3 = {0.f,0.f};
    v2 acB0 = {0.f,0.f}, acB1 = {0.f,0.f}, acB2 = {0.f,0.f}, acB3 = {0.f,0.f};

    struct U4 { v2 u0, u1, u2, u3; };

    // load av (SMEM pairs) + w quads, compute u for one site
    auto load_u = [&](const float* ap, const float* wq) -> U4 {
        const v2 a0 = *(const v2*)(ap + 0),  a1 = *(const v2*)(ap + 2);
        const v2 a2 = *(const v2*)(ap + 4),  a3 = *(const v2*)(ap + 6);
        const v2 a4 = *(const v2*)(ap + 8),  a5 = *(const v2*)(ap + 10);
        const v2 a6 = *(const v2*)(ap + 12), a7 = *(const v2*)(ap + 14);
        const float4 Q0 = *(const float4*)(wq);
        const float4 Q1 = *(const float4*)(wq + 256);
        const v2 W0 = {Q0.x, Q0.y}, W1 = {Q0.z, Q0.w};
        const v2 W2 = {Q1.x, Q1.y}, W3 = {Q1.z, Q1.w};
        U4 r;
        r.u0 = pk_mul_s_lo(a0, W0);
        r.u0 = pk_fma_s_hi(a0, W1, r.u0);
        r.u0 = pk_fma_s_lo(a1, W2, r.u0);
        r.u0 = pk_fma_s_hi(a1, W3, r.u0);
        r.u1 = pk_mul_s_lo(a2, W0);
        r.u1 = pk_fma_s_hi(a2, W1, r.u1);
        r.u1 = pk_fma_s_lo(a3, W2, r.u1);
        r.u1 = pk_fma_s_hi(a3, W3, r.u1);
        r.u2 = pk_mul_s_lo(a4, W0);
        r.u2 = pk_fma_s_hi(a4, W1, r.u2);
        r.u2 = pk_fma_s_lo(a5, W2, r.u2);
        r.u2 = pk_fma_s_hi(a5, W3, r.u2);
        r.u3 = pk_mul_s_lo(a6, W0);
        r.u3 = pk_fma_s_hi(a6, W1, r.u3);
        r.u3 = pk_fma_s_lo(a7, W2, r.u3);
        r.u3 = pk_fma_s_hi(a7, W3, r.u3);
        return r;
    };

    auto dotp = [&](const U4& U) -> float {
        v2 ds = pk_mul(U.u0, cv0);
        ds = pk_fma(U.u1, cv1, ds);
        ds = pk_fma(U.u2, cv2, ds);
        ds = pk_fma(U.u3, cv3, ds);
        return ds.x + ds.y;
    };

    auto dpp4 = [](float e) -> float {
        float s = e;
        s = DPP_ADDF(s, 0xB1);    // xor1
        s = DPP_ADDF(s, 0x4E);    // xor2
        s = DPP_ADDF(s, 0x141);   // xor4
        s = DPP_ADDF(s, 0x140);   // xor8
        return s;
    };
    auto swz16 = [](float s) -> float {
        return __builtin_bit_cast(float,
            __builtin_amdgcn_ds_swizzle(__builtin_bit_cast(int, s), 0x401F));
    };

    const float* wbase = w3 + l64 * 4;
    // stream B = stream A + 16 capsules: +262144 floats (input), +73728 (w3)

    for (int n = 0; n < 16; ++n) {
        const float* anA = ipb + n * 16384;

#pragma unroll
        for (int kp = 0; kp < 4; ++kp) {            // kl pairs (0,1)..(6,7)
            const int kl0 = 2 * kp, kl1 = kl0 + 1;
            const float* apA0 = anA + (kl0 / 3) * 512 + (kl0 % 3) * 16;
            const float* apA1 = anA + (kl1 / 3) * 512 + (kl1 % 3) * 16;
            const float* wqA0 = wbase + (size_t)(n * 9 + kl0) * 512;
            const float* wqA1 = wqA0 + 512;

            U4 UA0 = load_u(apA0,          wqA0);
            U4 UA1 = load_u(apA1,          wqA1);
            U4 UB0 = load_u(apA0 + 262144, wqA0 + 73728);
            U4 UB1 = load_u(apA1 + 262144, wqA1 + 73728);

            float dA0 = dotp(UA0), dA1 = dotp(UA1);
            float dB0 = dotp(UB0), dB1 = dotp(UB1);

            // cluster the 4 cross-half exchanges (one lgkm drain serves all)
            float xA0 = __shfl_xor(dA0, 32, 64);
            float xA1 = __shfl_xor(dA1, 32, 64);
            float xB0 = __shfl_xor(dB0, 32, 64);
            float xB1 = __shfl_xor(dB1, 32, 64);

            float eA0 = __expf(dA0 + xA0);
            float eA1 = __expf(dA1 + xA1);
            float eB0 = __expf(dB0 + xB0);
            float eB1 = __expf(dB1 + xB1);

            float sA0 = dpp4(eA0), sA1 = dpp4(eA1);
            float sB0 = dpp4(eB0), sB1 = dpp4(eB1);

            // cluster the 4 xor16 swizzles
            float wA0 = swz16(sA0), wA1 = swz16(sA1);
            float wB0 = swz16(sB0), wB1 = swz16(sB1);

            float pA0 = eA0 * __builtin_amdgcn_rcpf(sA0 + wA0);
            float pA1 = eA1 * __builtin_amdgcn_rcpf(sA1 + wA1);
            float pB0 = eB0 * __builtin_amdgcn_rcpf(sB0 + wB0);
            float pB1 = eB1 * __builtin_amdgcn_rcpf(sB1 + wB1);

            v2 qA0 = {pA0, pA0}, qA1 = {pA1, pA1};
            v2 qB0 = {pB0, pB0}, qB1 = {pB1, pB1};
            // accumulate in kl order (bit-identical to sequential kl loop)
            acA0 = pk_fma(qA0, UA0.u0, acA0);
            acA1 = pk_fma(qA0, UA0.u1, acA1);
            acA2 = pk_fma(qA0, UA0.u2, acA2);
            acA3 = pk_fma(qA0, UA0.u3, acA3);
            acA0 = pk_fma(qA1, UA1.u0, acA0);
            acA1 = pk_fma(qA1, UA1.u1, acA1);
            acA2 = pk_fma(qA1, UA1.u2, acA2);
            acA3 = pk_fma(qA1, UA1.u3, acA3);
            acB0 = pk_fma(qB0, UB0.u0, acB0);
            acB1 = pk_fma(qB0, UB0.u1, acB1);
            acB2 = pk_fma(qB0, UB0.u2, acB2);
            acB3 = pk_fma(qB0, UB0.u3, acB3);
            acB0 = pk_fma(qB1, UB1.u0, acB0);
            acB1 = pk_fma(qB1, UB1.u1, acB1);
            acB2 = pk_fma(qB1, UB1.u2, acB2);
            acB3 = pk_fma(qB1, UB1.u3, acB3);
        }

        {   // kl = 8 (row 2, col 2): 2 sites (one per stream)
            const float* apA = anA + 2 * 512 + 2 * 16;
            const float* wqA = wbase + (size_t)(n * 9 + 8) * 512;
            U4 UA = load_u(apA,          wqA);
            U4 UB = load_u(apA + 262144, wqA + 73728);
            float dA = dotp(UA), dB = dotp(UB);
            float xA = __shfl_xor(dA, 32, 64);
            float xB = __shfl_xor(dB, 32, 64);
            float eA = __expf(dA + xA);
            float eB = __expf(dB + xB);
            float sA = dpp4(eA), sB = dpp4(eB);
            float wA = swz16(sA), wB = swz16(sB);
            float pA = eA * __builtin_amdgcn_rcpf(sA + wA);
            float pB = eB * __builtin_amdgcn_rcpf(sB + wB);
            v2 qA = {pA, pA}, qB = {pB, pB};
            acA0 = pk_fma(qA, UA.u0, acA0);
            acA1 = pk_fma(qA, UA.u1, acA1);
            acA2 = pk_fma(qA, UA.u2, acA2);
            acA3 = pk_fma(qA, UA.u3, acA3);
            acB0 = pk_fma(qB, UB.u0, acB0);
            acB1 = pk_fma(qB, UB.u1, acB1);
            acB2 = pk_fma(qB, UB.u2, acB2);
            acB3 = pk_fma(qB, UB.u3, acB3);
        }
    }

    // merge streams
    v2 acc0 = acA0 + acB0;
    v2 acc1 = acA1 + acB1;
    v2 acc2 = acA2 + acB2;
    v2 acc3 = acA3 + acB3;

    // ---- fused LayerNorm: 8 local + cross-half exchange (shfl_xor 32) ----
    v2 s2 = (acc0 + acc1) + (acc2 + acc3);
    float s8  = s2.x + s2.y;
    float s16 = s8 + __shfl_xor(s8, 32, 64);
    float mu  = s16 * 0.0625f;
    v2 mv = {mu, mu};

    v2 vv = {0.f, 0.f};
    v2 t0 = acc0 - mv; vv = __builtin_elementwise_fma(t0, t0, vv);
    v2 t1 = acc1 - mv; vv = __builtin_elementwise_fma(t1, t1, vv);
    v2 t2 = acc2 - mv; vv = __builtin_elementwise_fma(t2, t2, vv);
    v2 t3 = acc3 - mv; vv = __builtin_elementwise_fma(t3, t3, vv);
    float v8  = vv.x + vv.y;
    float v16 = v8 + __shfl_xor(v8, 32, 64);
    float rstd = __builtin_amdgcn_rsqf(v16 * 0.0625f + 1e-5f);
    v2 rs2 = {rstd, rstd};

    const int db = 2 * half;
    float* op = out + (((size_t)b * 32 + m) * (HOUT * WOUT) + hw) * 16 + db;
    {
        v2 g  = *(const v2*)(gamma + 0 + db);
        v2 be = *(const v2*)(beta  + 0 + db);
        *(v2*)(op + 0)  = __builtin_elementwise_fma(t0 * rs2, g, be);
    }
    {
        v2 g  = *(const v2*)(gamma + 4 + db);
        v2 be = *(const v2*)(beta  + 4 + db);
        *(v2*)(op + 4)  = __builtin_elementwise_fma(t1 * rs2, g, be);
    }
    {
        v2 g  = *(const v2*)(gamma + 8 + db);
        v2 be = *(const v2*)(beta  + 8 + db);
        *(v2*)(op + 8)  = __builtin_elementwise_fma(t2 * rs2, g, be);
    }
    {
        v2 g  = *(const v2*)(gamma + 12 + db);
        v2 be = *(const v2*)(beta  + 12 + db);
        *(v2*)(op + 12) = __builtin_elementwise_fma(t3 * rs2, g, be);
    }
}

extern "C" void kernel_launch(void* const* d_in, const int* in_sizes, int n_in,
                              void* d_out, int out_size, void* d_ws, size_t ws_size,
                              hipStream_t stream) {
    const float* input = (const float*)d_in[0];
    const float* ncv   = (const float*)d_in[1];
    const float* wt    = (const float*)d_in[2];
    const float* gamma = (const float*)d_in[3];
    const float* beta  = (const float*)d_in[4];
    float* out = (float*)d_out;
    float* w3  = (float*)d_ws;                 // 576 KB

    prep_w<<<dim3(576), dim3(256), 0, stream>>>(wt, w3);
    caps_all<<<dim3(1800), dim3(256), 0, stream>>>(input, ncv, w3, gamma, beta, out);
}